// Round 4
// baseline (1981.590 us; speedup 1.0000x reference)
//
#include <hip/hip_runtime.h>
#include <hip/hip_bf16.h>
#include <math.h>

// PointNet++ SAModule: FPS -> ball query -> PointNetConv(MLP, max-agg)
// B=16 clouds, N=4096 pts, S=1024 centers, K=64 max nbrs, r=0.1, MLP 67->64->64->128.
// Correctness strategy: selection decisions (FPS argmax, ball membership, top-K)
// are made bit-exact vs numpy: __f*_rn intrinsics, (dx*dx+dy*dy)+dz*dz order,
// no FMA contraction, ties -> lower index. MLP math is fp32 (tolerance 0.3).

#define NB 16
#define NP 4096
#define FIN 64
#define NS 1024
#define KN 64
#define CAP 256

__device__ __forceinline__ float dist2e(float ax, float ay, float az,
                                        float bx, float by, float bz) {
    float dx = __fsub_rn(ax, bx);
    float dy = __fsub_rn(ay, by);
    float dz = __fsub_rn(az, bz);
    return __fadd_rn(__fadd_rn(__fmul_rn(dx, dx), __fmul_rn(dy, dy)),
                     __fmul_rn(dz, dz));
}

// ---------------- FPS: one block per cloud, 256 thr, 16 pts/thread ----------
__global__ __launch_bounds__(256) void fps_kernel(const float* __restrict__ pos,
                                                  int* __restrict__ fps_idx,
                                                  float* __restrict__ out_pos,
                                                  float* __restrict__ out_batch) {
    const int b = blockIdx.x;
    const int tid = threadIdx.x;
    const int lane = tid & 63;
    __shared__ float px[NP], py[NP], pz[NP];
    __shared__ float wbv[2][4];
    __shared__ int wbi[2][4];
    const float* p = pos + (size_t)b * NP * 3;
    float lx[16], ly[16], lz[16], md[16];
#pragma unroll
    for (int i = 0; i < 16; ++i) {
        int j = tid + (i << 8);
        float x = p[j * 3 + 0];
        float y = p[j * 3 + 1];
        float z = p[j * 3 + 2];
        px[j] = x; py[j] = y; pz[j] = z;
        lx[i] = x; ly[i] = y; lz[i] = z;
        md[i] = INFINITY;
    }
    __syncthreads();
    if (tid == 0) {
        fps_idx[b * NS] = 0;
        out_pos[(size_t)(b * NS) * 3 + 0] = px[0];
        out_pos[(size_t)(b * NS) * 3 + 1] = py[0];
        out_pos[(size_t)(b * NS) * 3 + 2] = pz[0];
    }
    int cur = 0;
    for (int s = 1; s < NS; ++s) {
        const float cx = px[cur], cy = py[cur], cz = pz[cur];
        float bv = -1.0f;
        int bi = 0x7fffffff;
#pragma unroll
        for (int i = 0; i < 16; ++i) {
            float d = dist2e(lx[i], ly[i], lz[i], cx, cy, cz);
            float m = md[i];
            m = d < m ? d : m;   // jnp.minimum (exact)
            md[i] = m;
            int j = tid + (i << 8);
            bool take = (m > bv) || (m == bv && j < bi);
            bv = take ? m : bv;
            bi = take ? j : bi;
        }
        // wave argmax (tie -> lower index, matches jnp.argmax)
#pragma unroll
        for (int off = 32; off > 0; off >>= 1) {
            float ov = __shfl_xor(bv, off, 64);
            int oi = __shfl_xor(bi, off, 64);
            bool take = (ov > bv) || (ov == bv && oi < bi);
            bv = take ? ov : bv;
            bi = take ? oi : bi;
        }
        const int buf = s & 1;  // double-buffered -> single barrier per step
        if (lane == 0) { wbv[buf][tid >> 6] = bv; wbi[buf][tid >> 6] = bi; }
        __syncthreads();
        bv = wbv[buf][0]; bi = wbi[buf][0];
#pragma unroll
        for (int w = 1; w < 4; ++w) {
            float ov = wbv[buf][w];
            int oi = wbi[buf][w];
            bool take = (ov > bv) || (ov == bv && oi < bi);
            bv = take ? ov : bv;
            bi = take ? oi : bi;
        }
        cur = bi;
        if (tid == 0) {
            fps_idx[b * NS + s] = cur;
            out_pos[(size_t)(b * NS + s) * 3 + 0] = px[cur];
            out_pos[(size_t)(b * NS + s) * 3 + 1] = py[cur];
            out_pos[(size_t)(b * NS + s) * 3 + 2] = pz[cur];
        }
    }
    for (int s = tid; s < NS; s += 256) out_batch[b * NS + s] = (float)b;
}

// ------------- ball query: 16 blocks/cloud, 64 centers/block, wave/center ----
__global__ __launch_bounds__(256) void ball_kernel(const float* __restrict__ pos,
                                                   const int* __restrict__ fps_idx,
                                                   int* __restrict__ nbr_cnt,
                                                   int* __restrict__ nbr_idx) {
    __shared__ float px[NP], py[NP], pz[NP];
    __shared__ float cd2[4][CAP];
    __shared__ int cix[4][CAP];
    const int tid = threadIdx.x;
    const int wv = tid >> 6, lane = tid & 63;
    const int b = blockIdx.x >> 4;
    const int grp = blockIdx.x & 15;
    const float* p = pos + (size_t)b * NP * 3;
    for (int e = tid; e < NP; e += 256) {
        px[e] = p[e * 3 + 0];
        py[e] = p[e * 3 + 1];
        pz[e] = p[e * 3 + 2];
    }
    __syncthreads();
    for (int i = 0; i < 16; ++i) {
        const int s = grp * 64 + i * 4 + wv;
        const int cen = b * NS + s;
        const int ci = fps_idx[cen];
        const float cx = px[ci], cy = py[ci], cz = pz[ci];
        int cnt = 0;
        for (int it = 0; it < NP / 64; ++it) {
            const int j = it * 64 + lane;
            float d2 = dist2e(cx, cy, cz, px[j], py[j], pz[j]);
            bool in = (d2 <= 0.01f);  // 0.01f == f32(0.1*0.1) from python
            unsigned long long m = __ballot(in);
            if (in) {
                int slot = cnt + __popcll(m & ((1ull << lane) - 1ull));
                if (slot < CAP) { cd2[wv][slot] = d2; cix[wv][slot] = j; }
            }
            cnt += __popcll(m);
        }
        if (cnt > CAP) cnt = CAP;  // unreachable for uniform data (E[cnt]~17)
        const int keep = cnt <= KN ? cnt : KN;
        if (lane == 0) nbr_cnt[cen] = keep;
        if (cnt <= KN) {
            if (lane < cnt) nbr_idx[(size_t)cen * KN + lane] = cix[wv][lane];
        } else {
            // exact K-nearest select: rank by (d2, idx) lexicographic,
            // matches lax.top_k(-d2) tie-break (lower index first)
            for (int e = lane; e < cnt; e += 64) {
                float d = cd2[wv][e];
                int id = cix[wv][e];
                int rank = 0;
                for (int q = 0; q < cnt; ++q) {
                    float dq = cd2[wv][q];
                    int iq = cix[wv][q];
                    rank += (dq < d || (dq == d && iq < id)) ? 1 : 0;
                }
                if (rank < KN) nbr_idx[(size_t)cen * KN + rank] = id;
            }
        }
    }
}

// ------------- PointNetConv: one block per center, valid pairs only ---------
__global__ __launch_bounds__(256) void conv_kernel(const float* __restrict__ pos,
                                                   const float* __restrict__ x,
                                                   const int* __restrict__ fps_idx,
                                                   const int* __restrict__ nbr_cnt,
                                                   const int* __restrict__ nbr_idx,
                                                   const float* __restrict__ W1,
                                                   const float* __restrict__ b1,
                                                   const float* __restrict__ W2,
                                                   const float* __restrict__ b2,
                                                   const float* __restrict__ W3,
                                                   const float* __restrict__ b3,
                                                   float* __restrict__ out) {
    const int cen = blockIdx.x;
    const int b = cen >> 10;  // NS = 1024
    const int tid = threadIdx.x;
    __shared__ float h1[KN][FIN + 1];
    __shared__ float h2[KN][FIN + 1];
    __shared__ float dpx[KN], dpy[KN], dpz[KN];
    __shared__ int jr[KN];
    __shared__ float omax[128];
    const int C = nbr_cnt[cen];
    const int ci = fps_idx[cen];
    const float* pb = pos + (size_t)b * NP * 3;
    if (tid < KN && tid < C) {
        int j = nbr_idx[(size_t)cen * KN + tid];
        jr[tid] = b * NP + j;
        float cx = pb[ci * 3 + 0], cy = pb[ci * 3 + 1], cz = pb[ci * 3 + 2];
        dpx[tid] = __fsub_rn(pb[j * 3 + 0], cx);
        dpy[tid] = __fsub_rn(pb[j * 3 + 1], cy);
        dpz[tid] = __fsub_rn(pb[j * 3 + 2], cz);
    }
    __syncthreads();
    const int c = tid & 63;
    const int pg = tid >> 6;
    {  // layer 1: h1 = relu(x_j @ W1[:64] + dp @ W1[64:67] + b1)
        const float w1x = W1[64 * 64 + c];
        const float w1y = W1[65 * 64 + c];
        const float w1z = W1[66 * 64 + c];
        const float bb = b1[c];
        for (int p = pg; p < C; p += 4) {
            const float* xr = x + (size_t)jr[p] * FIN;
            float acc = bb + dpx[p] * w1x + dpy[p] * w1y + dpz[p] * w1z;
            for (int f = 0; f < FIN; ++f) acc = fmaf(xr[f], W1[f * 64 + c], acc);
            h1[p][c] = acc > 0.f ? acc : 0.f;
        }
    }
    __syncthreads();
    {  // layer 2
        const float bb = b2[c];
        for (int p = pg; p < C; p += 4) {
            float acc = bb;
#pragma unroll
            for (int k = 0; k < 64; ++k) acc = fmaf(h1[p][k], W2[k * 64 + c], acc);
            h2[p][c] = acc > 0.f ? acc : 0.f;
        }
    }
    __syncthreads();
    const int o = tid & 127;
    const int g2 = tid >> 7;
    {  // layer 3 + max aggregation
        const float bb = b3[o];
        float mx = -INFINITY;
        for (int p = g2; p < C; p += 2) {
            float acc = bb;
#pragma unroll
            for (int k = 0; k < 64; ++k) acc = fmaf(h2[p][k], W3[k * 128 + o], acc);
            acc = acc > 0.f ? acc : 0.f;
            mx = mx > acc ? mx : acc;
        }
        if (g2 == 0) omax[o] = mx;
        __syncthreads();
        if (g2 == 1) {
            float other = omax[o];
            mx = mx > other ? mx : other;
            out[(size_t)cen * 128 + o] = mx;
        }
    }
}

extern "C" void kernel_launch(void* const* d_in, const int* in_sizes, int n_in,
                              void* d_out, int out_size, void* d_ws, size_t ws_size,
                              hipStream_t stream) {
    const float* x   = (const float*)d_in[0];
    const float* pos = (const float*)d_in[1];
    const float* W1  = (const float*)d_in[3];
    const float* b1  = (const float*)d_in[4];
    const float* W2  = (const float*)d_in[5];
    const float* b2  = (const float*)d_in[6];
    const float* W3  = (const float*)d_in[7];
    const float* b3  = (const float*)d_in[8];
    float* out = (float*)d_out;
    char* ws = (char*)d_ws;
    int* fps_idx = (int*)(ws);                     // 16384 * 4 B
    int* nbr_cnt = (int*)(ws + 16384 * 4);         // 16384 * 4 B
    int* nbr_idx = (int*)(ws + 16384 * 8);         // 16384 * 64 * 4 B = 4 MB
    float* out_feat  = out;                         // [16384][128]
    float* out_pos   = out + (size_t)16384 * 128;   // [16384][3]
    float* out_batch = out + (size_t)16384 * 131;   // [16384]
    fps_kernel<<<NB, 256, 0, stream>>>(pos, fps_idx, out_pos, out_batch);
    ball_kernel<<<NB * 16, 256, 0, stream>>>(pos, fps_idx, nbr_cnt, nbr_idx);
    conv_kernel<<<NB * NS, 256, 0, stream>>>(pos, x, fps_idx, nbr_cnt, nbr_idx,
                                             W1, b1, W2, b2, W3, b3, out_feat);
}

// Round 5
// 1300.208 us; speedup vs baseline: 1.5241x; 1.5241x over previous
//
#include <hip/hip_runtime.h>
#include <hip/hip_bf16.h>
#include <math.h>

// PointNet++ SAModule: FPS -> ball query -> PointNetConv(MLP, max-agg)
// B=16 clouds, N=4096 pts, S=1024 centers, K=64 max nbrs, r=0.1, MLP 67->64->64->128.
// Selection decisions (FPS argmax, ball membership, top-K) are bit-exact vs numpy:
// __f*_rn intrinsics, (dx*dx+dy*dy)+dz*dz order, no FMA, ties -> lower index.
// R5: FPS reduction rebuilt: u64 packed keys, DPP row_ror ladder (VALU-speed)
// + 1 ds_swizzle + 1 shfl_xor(32), winner xyz folded into the single-barrier
// broadcast. Distance math unchanged -> bit-identical selection.

#define NB 16
#define NP 4096
#define FIN 64
#define NS 1024
#define KN 64
#define CAP 256

__device__ __forceinline__ float dist2e(float ax, float ay, float az,
                                        float bx, float by, float bz) {
    float dx = __fsub_rn(ax, bx);
    float dy = __fsub_rn(ay, by);
    float dz = __fsub_rn(az, bz);
    return __fadd_rn(__fadd_rn(__fmul_rn(dx, dx), __fmul_rn(dy, dy)),
                     __fmul_rn(dz, dz));
}

// One DPP row-rotate reduce level on a packed u64 key (max). CTRL must be a
// compile-time literal (0x121=ror:1, 0x122=ror:2, 0x124=ror:4, 0x128=ror:8).
#define DPP_KEY_MAX(k, CTRL)                                                   \
    do {                                                                       \
        int _lo = (int)(unsigned)((k) & 0xFFFFFFFFull);                        \
        int _hi = (int)(unsigned)((k) >> 32);                                  \
        int _plo = __builtin_amdgcn_update_dpp(_lo, _lo, CTRL, 0xF, 0xF, false);\
        int _phi = __builtin_amdgcn_update_dpp(_hi, _hi, CTRL, 0xF, 0xF, false);\
        unsigned long long _nk =                                               \
            ((unsigned long long)(unsigned)_phi << 32) | (unsigned)_plo;       \
        if (_nk > (k)) (k) = _nk;                                              \
    } while (0)

// ---------------- FPS: one block per cloud, 256 thr, 16 pts/thread ----------
__global__ __launch_bounds__(256) void fps_kernel(const float* __restrict__ pos,
                                                  int* __restrict__ fps_idx,
                                                  float* __restrict__ out_pos,
                                                  float* __restrict__ out_batch) {
    const int b = blockIdx.x;
    const int tid = threadIdx.x;
    const int lane = tid & 63;
    const int wv = tid >> 6;
    __shared__ float px[NP], py[NP], pz[NP];
    __shared__ float bc[2][4][8];  // per-wave {key_lo, key_hi, x, y, z, pad}
    const float* p = pos + (size_t)b * NP * 3;
    float lx[16], ly[16], lz[16], md[16];
#pragma unroll
    for (int i = 0; i < 16; ++i) {
        int j = tid + (i << 8);
        float x = p[j * 3 + 0];
        float y = p[j * 3 + 1];
        float z = p[j * 3 + 2];
        px[j] = x; py[j] = y; pz[j] = z;
        lx[i] = x; ly[i] = y; lz[i] = z;
        md[i] = INFINITY;
    }
    __syncthreads();
    if (tid == 0) {
        fps_idx[b * NS] = 0;
        out_pos[(size_t)(b * NS) * 3 + 0] = px[0];
        out_pos[(size_t)(b * NS) * 3 + 1] = py[0];
        out_pos[(size_t)(b * NS) * 3 + 2] = pz[0];
    }
    float cx = px[0], cy = py[0], cz = pz[0];
    for (int s = 1; s < NS; ++s) {
        // local: md update + per-lane argmax (ascending i => strict > keeps
        // the lowest index, matching np.argmax first-occurrence)
        float bv = -1.0f;
        int bi = 0;
#pragma unroll
        for (int i = 0; i < 16; ++i) {
            float d = dist2e(lx[i], ly[i], lz[i], cx, cy, cz);
            float m = md[i];
            m = d < m ? d : m;   // jnp.minimum (exact)
            md[i] = m;
            bool take = (m > bv);
            bv = take ? m : bv;
            bi = take ? (tid + (i << 8)) : bi;
        }
        // pack: positive-f32 bits are order-isomorphic; ~idx => tie -> lower idx
        unsigned long long key =
            ((unsigned long long)__float_as_uint(bv) << 32) |
            (unsigned)(~(unsigned)bi);
        // wave reduce: 4 DPP row levels (16-lane rows) + xor16 + xor32
        DPP_KEY_MAX(key, 0x121);
        DPP_KEY_MAX(key, 0x122);
        DPP_KEY_MAX(key, 0x124);
        DPP_KEY_MAX(key, 0x128);
        {
            int _lo = (int)(unsigned)(key & 0xFFFFFFFFull);
            int _hi = (int)(unsigned)(key >> 32);
            int _plo = __builtin_amdgcn_ds_swizzle(_lo, 0x401F);  // lane ^ 16
            int _phi = __builtin_amdgcn_ds_swizzle(_hi, 0x401F);
            unsigned long long nk =
                ((unsigned long long)(unsigned)_phi << 32) | (unsigned)_plo;
            if (nk > key) key = nk;
        }
        {
            unsigned long long nk = __shfl_xor(key, 32, 64);      // lane ^ 32
            if (nk > key) key = nk;
        }
        const int buf = s & 1;  // double buffer -> one barrier per step is safe
        if (lane == 0) {
            int wi = (int)(~(unsigned)(key & 0xFFFFFFFFull));
            bc[buf][wv][0] = __uint_as_float((unsigned)(key & 0xFFFFFFFFull));
            bc[buf][wv][1] = __uint_as_float((unsigned)(key >> 32));
            bc[buf][wv][2] = px[wi];
            bc[buf][wv][3] = py[wi];
            bc[buf][wv][4] = pz[wi];
        }
        __syncthreads();
        // all lanes: select best of the 4 wave candidates (key + xyz folded)
        unsigned long long bk;
        float bx, by, bz;
        {
            float4 e = *(const float4*)&bc[buf][0][0];
            bk = ((unsigned long long)__float_as_uint(e.y) << 32) |
                 __float_as_uint(e.x);
            bx = e.z; by = e.w; bz = bc[buf][0][4];
        }
#pragma unroll
        for (int w = 1; w < 4; ++w) {
            float4 e = *(const float4*)&bc[buf][w][0];
            unsigned long long k2 =
                ((unsigned long long)__float_as_uint(e.y) << 32) |
                __float_as_uint(e.x);
            float z2 = bc[buf][w][4];
            bool take = (k2 > bk);
            bk = take ? k2 : bk;
            bx = take ? e.z : bx;
            by = take ? e.w : by;
            bz = take ? z2 : bz;
        }
        const int cur = (int)(~(unsigned)(bk & 0xFFFFFFFFull));
        cx = bx; cy = by; cz = bz;
        if (tid == 0) {
            fps_idx[b * NS + s] = cur;
            out_pos[(size_t)(b * NS + s) * 3 + 0] = bx;
            out_pos[(size_t)(b * NS + s) * 3 + 1] = by;
            out_pos[(size_t)(b * NS + s) * 3 + 2] = bz;
        }
    }
    for (int s = tid; s < NS; s += 256) out_batch[b * NS + s] = (float)b;
}

// ------------- ball query: 16 blocks/cloud, 64 centers/block, wave/center ----
__global__ __launch_bounds__(256) void ball_kernel(const float* __restrict__ pos,
                                                   const int* __restrict__ fps_idx,
                                                   int* __restrict__ nbr_cnt,
                                                   int* __restrict__ nbr_idx) {
    __shared__ float px[NP], py[NP], pz[NP];
    __shared__ float cd2[4][CAP];
    __shared__ int cix[4][CAP];
    const int tid = threadIdx.x;
    const int wv = tid >> 6, lane = tid & 63;
    const int b = blockIdx.x >> 4;
    const int grp = blockIdx.x & 15;
    const float* p = pos + (size_t)b * NP * 3;
    for (int e = tid; e < NP; e += 256) {
        px[e] = p[e * 3 + 0];
        py[e] = p[e * 3 + 1];
        pz[e] = p[e * 3 + 2];
    }
    __syncthreads();
    for (int i = 0; i < 16; ++i) {
        const int s = grp * 64 + i * 4 + wv;
        const int cen = b * NS + s;
        const int ci = fps_idx[cen];
        const float cx = px[ci], cy = py[ci], cz = pz[ci];
        int cnt = 0;
        for (int it = 0; it < NP / 64; ++it) {
            const int j = it * 64 + lane;
            float d2 = dist2e(cx, cy, cz, px[j], py[j], pz[j]);
            bool in = (d2 <= 0.01f);  // 0.01f == f32(0.1*0.1) from python
            unsigned long long m = __ballot(in);
            if (in) {
                int slot = cnt + __popcll(m & ((1ull << lane) - 1ull));
                if (slot < CAP) { cd2[wv][slot] = d2; cix[wv][slot] = j; }
            }
            cnt += __popcll(m);
        }
        if (cnt > CAP) cnt = CAP;  // unreachable for uniform data (E[cnt]~17)
        const int keep = cnt <= KN ? cnt : KN;
        if (lane == 0) nbr_cnt[cen] = keep;
        if (cnt <= KN) {
            if (lane < cnt) nbr_idx[(size_t)cen * KN + lane] = cix[wv][lane];
        } else {
            // exact K-nearest select: rank by (d2, idx) lexicographic,
            // matches lax.top_k(-d2) tie-break (lower index first)
            for (int e = lane; e < cnt; e += 64) {
                float d = cd2[wv][e];
                int id = cix[wv][e];
                int rank = 0;
                for (int q = 0; q < cnt; ++q) {
                    float dq = cd2[wv][q];
                    int iq = cix[wv][q];
                    rank += (dq < d || (dq == d && iq < id)) ? 1 : 0;
                }
                if (rank < KN) nbr_idx[(size_t)cen * KN + rank] = id;
            }
        }
    }
}

// ------------- PointNetConv: one block per center, valid pairs only ---------
__global__ __launch_bounds__(256) void conv_kernel(const float* __restrict__ pos,
                                                   const float* __restrict__ x,
                                                   const int* __restrict__ fps_idx,
                                                   const int* __restrict__ nbr_cnt,
                                                   const int* __restrict__ nbr_idx,
                                                   const float* __restrict__ W1,
                                                   const float* __restrict__ b1,
                                                   const float* __restrict__ W2,
                                                   const float* __restrict__ b2,
                                                   const float* __restrict__ W3,
                                                   const float* __restrict__ b3,
                                                   float* __restrict__ out) {
    const int cen = blockIdx.x;
    const int b = cen >> 10;  // NS = 1024
    const int tid = threadIdx.x;
    __shared__ float h1[KN][FIN + 1];
    __shared__ float h2[KN][FIN + 1];
    __shared__ float dpx[KN], dpy[KN], dpz[KN];
    __shared__ int jr[KN];
    __shared__ float omax[128];
    const int C = nbr_cnt[cen];
    const int ci = fps_idx[cen];
    const float* pb = pos + (size_t)b * NP * 3;
    if (tid < KN && tid < C) {
        int j = nbr_idx[(size_t)cen * KN + tid];
        jr[tid] = b * NP + j;
        float cx = pb[ci * 3 + 0], cy = pb[ci * 3 + 1], cz = pb[ci * 3 + 2];
        dpx[tid] = __fsub_rn(pb[j * 3 + 0], cx);
        dpy[tid] = __fsub_rn(pb[j * 3 + 1], cy);
        dpz[tid] = __fsub_rn(pb[j * 3 + 2], cz);
    }
    __syncthreads();
    const int c = tid & 63;
    const int pg = tid >> 6;
    {  // layer 1: h1 = relu(x_j @ W1[:64] + dp @ W1[64:67] + b1)
        const float w1x = W1[64 * 64 + c];
        const float w1y = W1[65 * 64 + c];
        const float w1z = W1[66 * 64 + c];
        const float bb = b1[c];
        for (int p = pg; p < C; p += 4) {
            const float* xr = x + (size_t)jr[p] * FIN;
            float acc = bb + dpx[p] * w1x + dpy[p] * w1y + dpz[p] * w1z;
            for (int f = 0; f < FIN; ++f) acc = fmaf(xr[f], W1[f * 64 + c], acc);
            h1[p][c] = acc > 0.f ? acc : 0.f;
        }
    }
    __syncthreads();
    {  // layer 2
        const float bb = b2[c];
        for (int p = pg; p < C; p += 4) {
            float acc = bb;
#pragma unroll
            for (int k = 0; k < 64; ++k) acc = fmaf(h1[p][k], W2[k * 64 + c], acc);
            h2[p][c] = acc > 0.f ? acc : 0.f;
        }
    }
    __syncthreads();
    const int o = tid & 127;
    const int g2 = tid >> 7;
    {  // layer 3 + max aggregation
        const float bb = b3[o];
        float mx = -INFINITY;
        for (int p = g2; p < C; p += 2) {
            float acc = bb;
#pragma unroll
            for (int k = 0; k < 64; ++k) acc = fmaf(h2[p][k], W3[k * 128 + o], acc);
            acc = acc > 0.f ? acc : 0.f;
            mx = mx > acc ? mx : acc;
        }
        if (g2 == 0) omax[o] = mx;
        __syncthreads();
        if (g2 == 1) {
            float other = omax[o];
            mx = mx > other ? mx : other;
            out[(size_t)cen * 128 + o] = mx;
        }
    }
}

extern "C" void kernel_launch(void* const* d_in, const int* in_sizes, int n_in,
                              void* d_out, int out_size, void* d_ws, size_t ws_size,
                              hipStream_t stream) {
    const float* x   = (const float*)d_in[0];
    const float* pos = (const float*)d_in[1];
    const float* W1  = (const float*)d_in[3];
    const float* b1  = (const float*)d_in[4];
    const float* W2  = (const float*)d_in[5];
    const float* b2  = (const float*)d_in[6];
    const float* W3  = (const float*)d_in[7];
    const float* b3  = (const float*)d_in[8];
    float* out = (float*)d_out;
    char* ws = (char*)d_ws;
    int* fps_idx = (int*)(ws);                     // 16384 * 4 B
    int* nbr_cnt = (int*)(ws + 16384 * 4);         // 16384 * 4 B
    int* nbr_idx = (int*)(ws + 16384 * 8);         // 16384 * 64 * 4 B = 4 MB
    float* out_feat  = out;                         // [16384][128]
    float* out_pos   = out + (size_t)16384 * 128;   // [16384][3]
    float* out_batch = out + (size_t)16384 * 131;   // [16384]
    fps_kernel<<<NB, 256, 0, stream>>>(pos, fps_idx, out_pos, out_batch);
    ball_kernel<<<NB * 16, 256, 0, stream>>>(pos, fps_idx, nbr_cnt, nbr_idx);
    conv_kernel<<<NB * NS, 256, 0, stream>>>(pos, x, fps_idx, nbr_cnt, nbr_idx,
                                             W1, b1, W2, b2, W3, b3, out_feat);
}